// Round 3
// baseline (334.519 us; speedup 1.0000x reference)
//
#include <hip/hip_runtime.h>
#include <math.h>

#define D_DIM 2048
#define R_DIM 512
#define E_NUM 8
#define B_NUM 8
#define S_NUM 2048
#define M_DIM 16384
#define LN_EPS 1e-5f

typedef __attribute__((ext_vector_type(8))) short bf16x8;
typedef __attribute__((ext_vector_type(4))) float f32x4;

// Manual RNE float->bf16 (inputs are finite/normal; no NaN path needed)
__device__ __forceinline__ unsigned short f2bf(float f) {
    unsigned u = __float_as_uint(f);
    return (unsigned short)((u + 0x7FFFu + ((u >> 16) & 1u)) >> 16);
}
__device__ __forceinline__ float bf2f(unsigned short h) {
    return __uint_as_float(((unsigned)h) << 16);
}

__device__ __forceinline__ void gload_lds16(const void* g, void* l) {
    __builtin_amdgcn_global_load_lds(
        (const __attribute__((address_space(1))) void*)g,
        (__attribute__((address_space(3))) void*)l, 16, 0, 0);
}

// ---------------------------------------------------------------------------
// Pass 1: per-token LayerNorm; overwrite the first 4KB of each 8KB fp32 row
// with 2048 x bf16 of LN(x) (hi only — x-rounding error is i.i.d. and washes
// out by sqrt(M) in the S-reduction; only w1 needs the hi+lo split).
// All reads of `row` are consumed before the stats barrier; writes after.
// ---------------------------------------------------------------------------
__global__ __launch_bounds__(256) void ln_split_kernel(float* __restrict__ x,
                                                       const float* __restrict__ gamma,
                                                       const float* __restrict__ beta) {
    __shared__ float sred[8];
    const int t = threadIdx.x;
    float* row = x + (size_t)blockIdx.x * D_DIM;
    const float4 v0  = ((const float4*)row)[t];
    const float4 v1  = ((const float4*)row)[t + 256];
    const float4 g0  = ((const float4*)gamma)[t];
    const float4 g1  = ((const float4*)gamma)[t + 256];
    const float4 be0 = ((const float4*)beta)[t];
    const float4 be1 = ((const float4*)beta)[t + 256];

    float s  = v0.x + v0.y + v0.z + v0.w + v1.x + v1.y + v1.z + v1.w;
    float sq = v0.x*v0.x + v0.y*v0.y + v0.z*v0.z + v0.w*v0.w
             + v1.x*v1.x + v1.y*v1.y + v1.z*v1.z + v1.w*v1.w;
#pragma unroll
    for (int off = 32; off > 0; off >>= 1) {
        s  += __shfl_down(s, off);
        sq += __shfl_down(sq, off);
    }
    if ((t & 63) == 0) { sred[(t >> 6) * 2] = s; sred[(t >> 6) * 2 + 1] = sq; }
    __syncthreads();            // also: every thread's row-reads are complete
    s  = sred[0] + sred[2] + sred[4] + sred[6];
    sq = sred[1] + sred[3] + sred[5] + sred[7];
    const float mu  = s * (1.f / D_DIM);
    const float var = sq * (1.f / D_DIM) - mu * mu;
    const float rs  = rsqrtf(var + LN_EPS);

    ushort4 h0, h1;
    h0.x = f2bf(fmaf((v0.x - mu) * rs, g0.x, be0.x));
    h0.y = f2bf(fmaf((v0.y - mu) * rs, g0.y, be0.y));
    h0.z = f2bf(fmaf((v0.z - mu) * rs, g0.z, be0.z));
    h0.w = f2bf(fmaf((v0.w - mu) * rs, g0.w, be0.w));
    h1.x = f2bf(fmaf((v1.x - mu) * rs, g1.x, be1.x));
    h1.y = f2bf(fmaf((v1.y - mu) * rs, g1.y, be1.y));
    h1.z = f2bf(fmaf((v1.z - mu) * rs, g1.z, be1.z));
    h1.w = f2bf(fmaf((v1.w - mu) * rs, g1.w, be1.w));

    ushort4* rowu = (ushort4*)row;
    rowu[t]       = h0;          // k = 4t .. 4t+3
    rowu[t + 256] = h1;          // k = 1024+4t ..
}

// ---------------------------------------------------------------------------
// Pass 2: w1[k][n] fp32 -> wT_hi[n][k], wT_lo[n][k] bf16 (transposed; split).
// ---------------------------------------------------------------------------
__global__ __launch_bounds__(256) void wsplit_kernel(const float* __restrict__ w1,
                                                     unsigned short* __restrict__ wt_hi,
                                                     unsigned short* __restrict__ wt_lo) {
    const int tid = blockIdx.x * 256 + threadIdx.x;   // 262144 = 512 n * 512 k4
    const int n  = tid >> 9;
    const int k4 = tid & 511;
    ushort4 h, l;
    unsigned short hh;
    float f;
    f = w1[(size_t)(k4 * 4 + 0) * R_DIM + n]; hh = f2bf(f); h.x = hh; l.x = f2bf(f - bf2f(hh));
    f = w1[(size_t)(k4 * 4 + 1) * R_DIM + n]; hh = f2bf(f); h.y = hh; l.y = f2bf(f - bf2f(hh));
    f = w1[(size_t)(k4 * 4 + 2) * R_DIM + n]; hh = f2bf(f); h.z = hh; l.z = f2bf(f - bf2f(hh));
    f = w1[(size_t)(k4 * 4 + 3) * R_DIM + n]; hh = f2bf(f); h.w = hh; l.w = f2bf(f - bf2f(hh));
    ((ushort4*)wt_hi)[(size_t)n * 512 + k4] = h;
    ((ushort4*)wt_lo)[(size_t)n * 512 + k4] = l;
}

// ---------------------------------------------------------------------------
// Main GEMM: C[16384][512] = xn_hi @ (w_hi + w_lo) via 2-product bf16 MFMA.
// 128x128x64 tile, 4 waves (2x2 of 64x64), 48KB LDS single-buffer,
// global_load_lds(16B) linear-dest + pre-swizzled source; XOR-swizzled
// ds_read_b128 (rule #21 both-sides pattern).
// Epilogue: +b1, exact GELU, column-sum over 128 rows -> atomicAdd hsum.
// ---------------------------------------------------------------------------
#define BM 128
#define BN 128
#define BK 64

__global__ __launch_bounds__(256, 2) void gemm_kernel(
    const unsigned short* __restrict__ xs,   // [M] rows: 2048 bf16 hi in first 4KB of 8KB stride
    const unsigned short* __restrict__ wt_hi,
    const unsigned short* __restrict__ wt_lo,
    const float* __restrict__ b1,
    float* __restrict__ hsum) {
    __shared__ __align__(16) unsigned short lds[3 * 8192];  // A | B_hi | B_lo, 16KB each

    const int t = threadIdx.x, lane = t & 63, wid = t >> 6;
    // XCD swizzle: XCD x = bid&7 owns n-column x>>1 (B-panel 2MB -> L2-resident)
    // and m-half x&1. Bijective for 512 blocks.
    const int xcd = blockIdx.x & 7, i0 = blockIdx.x >> 3;
    const int n0 = (xcd >> 1) * BN;
    const int m0 = ((xcd & 1) * 64 + i0) * BM;
    const int mw = wid >> 1, nw = wid & 1;
    const int fr = lane & 15, kg = lane >> 4, fr7 = lane & 7;

    f32x4 acc[4][4];
#pragma unroll
    for (int i = 0; i < 4; ++i)
#pragma unroll
        for (int j = 0; j < 4; ++j) acc[i][j] = (f32x4){0.f, 0.f, 0.f, 0.f};

    // Staging geometry: one 16KB tile (128 rows x 128B) = 16 x 1KB instrs;
    // wave wid issues instrs wid*4..wid*4+3 per tile. Linear LDS dest
    // (base + lane*16 by HW); source slot pre-XOR-swizzled by row&7.
    int srow[4], sgo[4], ldso[4];
#pragma unroll
    for (int ii = 0; ii < 4; ++ii) {
        const int idx = wid * 4 + ii;
        const int o = (idx << 10) + (lane << 4);
        const int r = o >> 7, sl = (o >> 4) & 7;
        srow[ii] = r;
        sgo[ii]  = ((sl ^ (r & 7)) << 4);
        ldso[ii] = (idx << 10);
    }

    int aoff[4], boff[4];
#pragma unroll
    for (int f = 0; f < 4; ++f) {
        aoff[f] = (mw * 64 + f * 16 + fr) * 128;
        boff[f] = (nw * 64 + f * 16 + fr) * 128;
    }
    const char* ldsb = (const char*)lds;

    for (int k0b = 0; k0b < D_DIM * 2; k0b += BK * 2) {   // byte offset along k
        __syncthreads();   // previous tile's compute done before overwrite
#pragma unroll
        for (int ii = 0; ii < 4; ++ii) {
            const char* a  = (const char*)xs    + (size_t)(m0 + srow[ii]) * 8192 + k0b + sgo[ii];
            const char* bh = (const char*)wt_hi + (size_t)(n0 + srow[ii]) * 4096 + k0b + sgo[ii];
            const char* bl = (const char*)wt_lo + (size_t)(n0 + srow[ii]) * 4096 + k0b + sgo[ii];
            gload_lds16(a,  (char*)lds +     0 + ldso[ii]);
            gload_lds16(bh, (char*)lds + 16384 + ldso[ii]);
            gload_lds16(bl, (char*)lds + 32768 + ldso[ii]);
        }
        __syncthreads();   // compiler drains vmcnt(0) before barrier: data ready
#pragma unroll
        for (int kk = 0; kk < 2; ++kk) {
            const int sw = ((kk * 4 + kg) ^ fr7) << 4;   // swizzled 16B k-slot
            bf16x8 ah[4], bh[4], bl[4];
#pragma unroll
            for (int f = 0; f < 4; ++f) {
                ah[f] = *(const bf16x8*)(ldsb +     0 + aoff[f] + sw);
                bh[f] = *(const bf16x8*)(ldsb + 16384 + boff[f] + sw);
                bl[f] = *(const bf16x8*)(ldsb + 32768 + boff[f] + sw);
            }
#pragma unroll
            for (int i = 0; i < 4; ++i)
#pragma unroll
                for (int j = 0; j < 4; ++j) {
                    acc[i][j] = __builtin_amdgcn_mfma_f32_16x16x32_bf16(ah[i], bh[j], acc[i][j], 0, 0, 0);
                    acc[i][j] = __builtin_amdgcn_mfma_f32_16x16x32_bf16(ah[i], bl[j], acc[i][j], 0, 0, 0);
                }
        }
    }

    // Epilogue: y = acc + b1; h = exact GELU(y); per-column partial sums.
    // D layout (m89-verified): col = lane&15 (n), row = (lane>>4)*4 + reg (m).
    __syncthreads();
    float* red = (float*)lds;            // [wid*4+kg][64 cols]
    float pn[4];
#pragma unroll
    for (int j = 0; j < 4; ++j) pn[j] = 0.f;
#pragma unroll
    for (int j = 0; j < 4; ++j) {
        const float bb = b1[n0 + nw * 64 + j * 16 + fr];
#pragma unroll
        for (int i = 0; i < 4; ++i)
#pragma unroll
            for (int r = 0; r < 4; ++r) {
                const float y = acc[i][j][r] + bb;
                pn[j] += 0.5f * y * (1.f + erff(y * 0.70710678118654752f));
            }
    }
#pragma unroll
    for (int j = 0; j < 4; ++j)
        red[(wid * 4 + kg) * 64 + j * 16 + fr] = pn[j];
    __syncthreads();
    if (t < 128) {
        const int nw2 = t >> 6, cl = t & 63;
        float s2 = 0.f;
#pragma unroll
        for (int mw2 = 0; mw2 < 2; ++mw2)
#pragma unroll
            for (int g = 0; g < 4; ++g)
                s2 += red[((mw2 * 2 + nw2) * 4 + g) * 64 + cl];
        atomicAdd(&hsum[(m0 >> 11) * R_DIM + n0 + t], s2);
    }
}

// ---------------------------------------------------------------------------
// Router stage 1: brd[b][q] = sum_r hsum[b][r] * w2[r][q]
// ---------------------------------------------------------------------------
__global__ void router1_kernel(const float* __restrict__ hsum,
                               const float* __restrict__ w2,
                               float* __restrict__ brd) {
    const int q  = blockIdx.x * 64 + threadIdx.x;
    const int r0 = blockIdx.y * 64;
    float acc[8] = {0, 0, 0, 0, 0, 0, 0, 0};
    for (int r = r0 + threadIdx.y; r < r0 + 64; r += 4) {
        const float w = w2[(size_t)r * R_DIM + q];
#pragma unroll
        for (int b = 0; b < 8; ++b) acc[b] = fmaf(hsum[b * R_DIM + r], w, acc[b]);
    }
    __shared__ float sred[4][8][64];
#pragma unroll
    for (int b = 0; b < 8; ++b) sred[threadIdx.y][b][threadIdx.x] = acc[b];
    __syncthreads();
    if (threadIdx.y == 0) {
#pragma unroll
        for (int b = 0; b < 8; ++b) {
            float s = sred[0][b][threadIdx.x] + sred[1][b][threadIdx.x]
                    + sred[2][b][threadIdx.x] + sred[3][b][threadIdx.x];
            atomicAdd(&brd[b * R_DIM + q], s);
        }
    }
}

// ---------------------------------------------------------------------------
// Router stage 2: logits, BCE loss, argmax counts, mode. One wave.
// ---------------------------------------------------------------------------
__global__ void router2_kernel(const float* __restrict__ brd,
                               const float* __restrict__ b2,
                               const float* __restrict__ wr,
                               const float* __restrict__ br,
                               float* __restrict__ out) {
    __shared__ float lg[64];
    const int t = threadIdx.x;            // 64 threads
    const int b = t >> 3, e = t & 7;
    float s = br[e];
    for (int q = 0; q < R_DIM; ++q) {
        const float v = fmaf((float)S_NUM, b2[q], brd[b * R_DIM + q]);
        s = fmaf(v, wr[q * E_NUM + e], s);
    }
    lg[t] = s;
    __syncthreads();
    if (t == 0) {
        int cnt[8] = {0, 0, 0, 0, 0, 0, 0, 0};
        float loss = 0.f;
        for (int bb = 0; bb < 8; ++bb) {
            int best = 0;
            float bv = lg[bb * 8];
            for (int ee = 1; ee < 8; ++ee)
                if (lg[bb * 8 + ee] > bv) { bv = lg[bb * 8 + ee]; best = ee; }
            cnt[best]++;
            for (int ee = 0; ee < 8; ++ee) {
                const float xv = lg[bb * 8 + ee];
                loss += fmaxf(xv, 0.f) + log1pf(expf(-fabsf(xv))) - (ee == best ? xv : 0.f);
            }
        }
        out[0] = loss * (1.f / 64.f);
        int ni = 0;
        for (int ee = 1; ee < 8; ++ee)
            if (cnt[ee] > cnt[ni]) ni = ee;   // first max == smallest on ties
        out[1] = (float)ni;
    }
}

extern "C" void kernel_launch(void* const* d_in, const int* in_sizes, int n_in,
                              void* d_out, int out_size, void* d_ws, size_t ws_size,
                              hipStream_t stream) {
    float* x           = (float*)d_in[0];   // normalized+bf16-packed in place
    const float* gamma = (const float*)d_in[1];
    const float* beta  = (const float*)d_in[2];
    const float* w1    = (const float*)d_in[3];
    const float* b1    = (const float*)d_in[4];
    const float* w2    = (const float*)d_in[5];
    const float* b2    = (const float*)d_in[6];
    const float* wr    = (const float*)d_in[7];
    const float* br    = (const float*)d_in[8];
    float* out = (float*)d_out;
    float* ws  = (float*)d_ws;

    float* hsum = ws;              // 4096 floats
    float* brd  = ws + 4096;       // 4096 floats
    unsigned short* wt_hi = (unsigned short*)(ws + 8192);     // 1M ushort (2MB)
    unsigned short* wt_lo = wt_hi + (size_t)R_DIM * D_DIM;    // 1M ushort (2MB)

    hipMemsetAsync(ws, 0, 8192 * sizeof(float), stream);
    ln_split_kernel<<<dim3(M_DIM), dim3(256), 0, stream>>>(x, gamma, beta);
    wsplit_kernel<<<dim3(1024), dim3(256), 0, stream>>>(w1, wt_hi, wt_lo);
    gemm_kernel<<<dim3(512), dim3(256), 0, stream>>>(
        (const unsigned short*)x, wt_hi, wt_lo, b1, hsum);
    router1_kernel<<<dim3(8, 8), dim3(64, 4), 0, stream>>>(hsum, w2, brd);
    router2_kernel<<<dim3(1), dim3(64), 0, stream>>>(brd, b2, wr, br, out);
}

// Round 4
// 307.889 us; speedup vs baseline: 1.0865x; 1.0865x over previous
//
#include <hip/hip_runtime.h>
#include <math.h>

#define D_DIM 2048
#define R_DIM 512
#define E_NUM 8
#define B_NUM 8
#define S_NUM 2048
#define M_DIM 16384
#define LN_EPS 1e-5f

typedef __attribute__((ext_vector_type(8))) short bf16x8;
typedef __attribute__((ext_vector_type(4))) float f32x4;

// Manual RNE float->bf16 (inputs finite/normal; no NaN path needed)
__device__ __forceinline__ unsigned short f2bf(float f) {
    unsigned u = __float_as_uint(f);
    return (unsigned short)((u + 0x7FFFu + ((u >> 16) & 1u)) >> 16);
}

__device__ __forceinline__ void gload_lds16(const void* g, void* l) {
    __builtin_amdgcn_global_load_lds(
        (const __attribute__((address_space(1))) void*)g,
        (__attribute__((address_space(3))) void*)l, 16, 0, 0);
}

// ---------------------------------------------------------------------------
// Fused prep kernel, one dispatch:
//   blocks [0, 16384):      per-token LayerNorm -> bf16 in place (first 4KB/row)
//   blocks [16384, 17408):  w1[k][n] fp32 -> wT[n][k] bf16 (transpose + round)
//   blocks [17408, 17440):  zero hsum+brd (8192 floats)
// ---------------------------------------------------------------------------
__global__ __launch_bounds__(256) void prep_kernel(float* __restrict__ x,
                                                   const float* __restrict__ gamma,
                                                   const float* __restrict__ beta,
                                                   const float* __restrict__ w1,
                                                   unsigned short* __restrict__ wt,
                                                   float* __restrict__ zbuf) {
    const int t = threadIdx.x;
    if (blockIdx.x < M_DIM) {
        // ---- LayerNorm + bf16 pack, in place ----
        __shared__ float sred[8];
        float* row = x + (size_t)blockIdx.x * D_DIM;
        const float4 v0  = ((const float4*)row)[t];
        const float4 v1  = ((const float4*)row)[t + 256];
        const float4 g0  = ((const float4*)gamma)[t];
        const float4 g1  = ((const float4*)gamma)[t + 256];
        const float4 be0 = ((const float4*)beta)[t];
        const float4 be1 = ((const float4*)beta)[t + 256];

        float s  = v0.x + v0.y + v0.z + v0.w + v1.x + v1.y + v1.z + v1.w;
        float sq = v0.x*v0.x + v0.y*v0.y + v0.z*v0.z + v0.w*v0.w
                 + v1.x*v1.x + v1.y*v1.y + v1.z*v1.z + v1.w*v1.w;
#pragma unroll
        for (int off = 32; off > 0; off >>= 1) {
            s  += __shfl_down(s, off);
            sq += __shfl_down(sq, off);
        }
        if ((t & 63) == 0) { sred[(t >> 6) * 2] = s; sred[(t >> 6) * 2 + 1] = sq; }
        __syncthreads();            // also: all reads of `row` are complete
        s  = sred[0] + sred[2] + sred[4] + sred[6];
        sq = sred[1] + sred[3] + sred[5] + sred[7];
        const float mu  = s * (1.f / D_DIM);
        const float var = sq * (1.f / D_DIM) - mu * mu;
        const float rs  = rsqrtf(var + LN_EPS);

        ushort4 h0, h1;
        h0.x = f2bf(fmaf((v0.x - mu) * rs, g0.x, be0.x));
        h0.y = f2bf(fmaf((v0.y - mu) * rs, g0.y, be0.y));
        h0.z = f2bf(fmaf((v0.z - mu) * rs, g0.z, be0.z));
        h0.w = f2bf(fmaf((v0.w - mu) * rs, g0.w, be0.w));
        h1.x = f2bf(fmaf((v1.x - mu) * rs, g1.x, be1.x));
        h1.y = f2bf(fmaf((v1.y - mu) * rs, g1.y, be1.y));
        h1.z = f2bf(fmaf((v1.z - mu) * rs, g1.z, be1.z));
        h1.w = f2bf(fmaf((v1.w - mu) * rs, g1.w, be1.w));

        ushort4* rowu = (ushort4*)row;
        rowu[t]       = h0;          // k = 4t .. 4t+3
        rowu[t + 256] = h1;          // k = 1024+4t ..
    } else if (blockIdx.x < M_DIM + 1024) {
        // ---- w1 transpose + bf16 round: wT[n][k] ----
        const int tid = (blockIdx.x - M_DIM) * 256 + t;   // 262144 = 512 n * 512 k4
        const int n  = tid >> 9;
        const int k4 = tid & 511;
        ushort4 h;
        h.x = f2bf(w1[(size_t)(k4 * 4 + 0) * R_DIM + n]);
        h.y = f2bf(w1[(size_t)(k4 * 4 + 1) * R_DIM + n]);
        h.z = f2bf(w1[(size_t)(k4 * 4 + 2) * R_DIM + n]);
        h.w = f2bf(w1[(size_t)(k4 * 4 + 3) * R_DIM + n]);
        ((ushort4*)wt)[(size_t)n * 512 + k4] = h;
    } else {
        // ---- zero hsum (4096) + brd (4096) ----
        zbuf[(blockIdx.x - M_DIM - 1024) * 256 + t] = 0.f;
    }
}

// ---------------------------------------------------------------------------
// Main GEMM: C[16384][512] = xn_hi @ w_hi (single-product bf16 MFMA).
// 128x128x64 tile, 4 waves (2x2 of 64x64), 32KB LDS single-buffer,
// global_load_lds(16B) linear-dest + pre-swizzled source; XOR-swizzled
// ds_read_b128 (both-sides swizzle, HW-verified by round-3 absmax=0).
// Epilogue: +b1, exact GELU, column-sum over 128 rows -> atomicAdd hsum.
// ---------------------------------------------------------------------------
#define BM 128
#define BN 128
#define BK 64

__global__ __launch_bounds__(256, 2) void gemm_kernel(
    const unsigned short* __restrict__ xs,   // [M] rows: 2048 bf16 in first 4KB of 8KB stride
    const unsigned short* __restrict__ wt,   // [N][K] bf16, 4KB rows
    const float* __restrict__ b1,
    float* __restrict__ hsum) {
    __shared__ __align__(16) unsigned short lds[2 * 8192];  // A | B, 16KB each

    const int t = threadIdx.x, lane = t & 63, wid = t >> 6;
    // XCD swizzle: XCD x = bid&7 owns n-column x>>1 (B-panel 2MB -> L2-resident)
    // and m-half x&1. Bijective for 512 blocks.
    const int xcd = blockIdx.x & 7, i0 = blockIdx.x >> 3;
    const int n0 = (xcd >> 1) * BN;
    const int m0 = ((xcd & 1) * 64 + i0) * BM;
    const int mw = wid >> 1, nw = wid & 1;
    const int fr = lane & 15, kg = lane >> 4, fr7 = lane & 7;

    f32x4 acc[4][4];
#pragma unroll
    for (int i = 0; i < 4; ++i)
#pragma unroll
        for (int j = 0; j < 4; ++j) acc[i][j] = (f32x4){0.f, 0.f, 0.f, 0.f};

    // Staging geometry: one 16KB tile (128 rows x 128B) = 16 x 1KB instrs;
    // wave wid issues instrs wid*4..wid*4+3 per tile. Linear LDS dest
    // (base + lane*16 by HW); source slot pre-XOR-swizzled by row&7.
    int srow[4], sgo[4], ldso[4];
#pragma unroll
    for (int ii = 0; ii < 4; ++ii) {
        const int idx = wid * 4 + ii;
        const int o = (idx << 10) + (lane << 4);
        const int r = o >> 7, sl = (o >> 4) & 7;
        srow[ii] = r;
        sgo[ii]  = ((sl ^ (r & 7)) << 4);
        ldso[ii] = (idx << 10);
    }

    int aoff[4], boff[4];
#pragma unroll
    for (int f = 0; f < 4; ++f) {
        aoff[f] = (mw * 64 + f * 16 + fr) * 128;
        boff[f] = (nw * 64 + f * 16 + fr) * 128;
    }
    const char* ldsb = (const char*)lds;

    for (int k0b = 0; k0b < D_DIM * 2; k0b += BK * 2) {   // byte offset along k
        __syncthreads();   // previous tile's compute done before overwrite
#pragma unroll
        for (int ii = 0; ii < 4; ++ii) {
            const char* a = (const char*)xs + (size_t)(m0 + srow[ii]) * 8192 + k0b + sgo[ii];
            const char* b = (const char*)wt + (size_t)(n0 + srow[ii]) * 4096 + k0b + sgo[ii];
            gload_lds16(a, (char*)lds +     0 + ldso[ii]);
            gload_lds16(b, (char*)lds + 16384 + ldso[ii]);
        }
        __syncthreads();   // compiler drains vmcnt(0) before barrier: data ready
#pragma unroll
        for (int kk = 0; kk < 2; ++kk) {
            const int sw = ((kk * 4 + kg) ^ fr7) << 4;   // swizzled 16B k-slot
            bf16x8 ah[4], bh[4];
#pragma unroll
            for (int f = 0; f < 4; ++f) {
                ah[f] = *(const bf16x8*)(ldsb +     0 + aoff[f] + sw);
                bh[f] = *(const bf16x8*)(ldsb + 16384 + boff[f] + sw);
            }
#pragma unroll
            for (int i = 0; i < 4; ++i)
#pragma unroll
                for (int j = 0; j < 4; ++j)
                    acc[i][j] = __builtin_amdgcn_mfma_f32_16x16x32_bf16(ah[i], bh[j], acc[i][j], 0, 0, 0);
        }
    }

    // Epilogue: y = acc + b1; h = exact GELU(y); per-column partial sums.
    // D layout (m89-verified): col = lane&15 (n), row = (lane>>4)*4 + reg (m).
    __syncthreads();
    float* red = (float*)lds;            // [wid*4+kg][64 cols]
    float pn[4];
#pragma unroll
    for (int j = 0; j < 4; ++j) pn[j] = 0.f;
#pragma unroll
    for (int j = 0; j < 4; ++j) {
        const float bb = b1[n0 + nw * 64 + j * 16 + fr];
#pragma unroll
        for (int i = 0; i < 4; ++i)
#pragma unroll
            for (int r = 0; r < 4; ++r) {
                const float y = acc[i][j][r] + bb;
                pn[j] += 0.5f * y * (1.f + erff(y * 0.70710678118654752f));
            }
    }
#pragma unroll
    for (int j = 0; j < 4; ++j)
        red[(wid * 4 + kg) * 64 + j * 16 + fr] = pn[j];
    __syncthreads();
    if (t < 128) {
        const int nw2 = t >> 6, cl = t & 63;
        float s2 = 0.f;
#pragma unroll
        for (int mw2 = 0; mw2 < 2; ++mw2)
#pragma unroll
            for (int g = 0; g < 4; ++g)
                s2 += red[((mw2 * 2 + nw2) * 4 + g) * 64 + cl];
        atomicAdd(&hsum[(m0 >> 11) * R_DIM + n0 + t], s2);
    }
}

// ---------------------------------------------------------------------------
// Router stage 1: brd[b][q] = sum_r hsum[b][r]*w2[r][q]  (+ S*b2[q], once)
// ---------------------------------------------------------------------------
__global__ void router1_kernel(const float* __restrict__ hsum,
                               const float* __restrict__ w2,
                               const float* __restrict__ b2,
                               float* __restrict__ brd) {
    const int q  = blockIdx.x * 64 + threadIdx.x;
    const int r0 = blockIdx.y * 64;
    float acc[8] = {0, 0, 0, 0, 0, 0, 0, 0};
    for (int r = r0 + threadIdx.y; r < r0 + 64; r += 4) {
        const float w = w2[(size_t)r * R_DIM + q];
#pragma unroll
        for (int b = 0; b < 8; ++b) acc[b] = fmaf(hsum[b * R_DIM + r], w, acc[b]);
    }
    __shared__ float sred[4][8][64];
#pragma unroll
    for (int b = 0; b < 8; ++b) sred[threadIdx.y][b][threadIdx.x] = acc[b];
    __syncthreads();
    if (threadIdx.y == 0) {
        const float bias2 = (blockIdx.y == 0) ? (float)S_NUM * b2[q] : 0.f;
#pragma unroll
        for (int b = 0; b < 8; ++b) {
            float s = sred[0][b][threadIdx.x] + sred[1][b][threadIdx.x]
                    + sred[2][b][threadIdx.x] + sred[3][b][threadIdx.x] + bias2;
            atomicAdd(&brd[b * R_DIM + q], s);
        }
    }
}

// ---------------------------------------------------------------------------
// Router stage 2: logits = brd@wr + br; BCE loss, argmax counts, mode.
// Block (64,8): q-dimension parallelized over 8 groups.
// ---------------------------------------------------------------------------
__global__ void router2_kernel(const float* __restrict__ brd,
                               const float* __restrict__ wr,
                               const float* __restrict__ br,
                               float* __restrict__ out) {
    __shared__ float part[8][64];
    __shared__ float lg[64];
    const int te = threadIdx.x;           // (b,e) pair
    const int qg = threadIdx.y;           // q-group
    const int b = te >> 3, e = te & 7;
    float s = 0.f;
    for (int q = qg; q < R_DIM; q += 8)
        s = fmaf(brd[b * R_DIM + q], wr[q * E_NUM + e], s);
    part[qg][te] = s;
    __syncthreads();
    if (qg == 0) {
        float v = br[e];
#pragma unroll
        for (int g = 0; g < 8; ++g) v += part[g][te];
        lg[te] = v;
    }
    __syncthreads();
    if (te == 0 && qg == 0) {
        int cnt[8] = {0, 0, 0, 0, 0, 0, 0, 0};
        float loss = 0.f;
        for (int bb = 0; bb < 8; ++bb) {
            int best = 0;
            float bv = lg[bb * 8];
            for (int ee = 1; ee < 8; ++ee)
                if (lg[bb * 8 + ee] > bv) { bv = lg[bb * 8 + ee]; best = ee; }
            cnt[best]++;
            for (int ee = 0; ee < 8; ++ee) {
                const float xv = lg[bb * 8 + ee];
                loss += fmaxf(xv, 0.f) + log1pf(expf(-fabsf(xv))) - (ee == best ? xv : 0.f);
            }
        }
        out[0] = loss * (1.f / 64.f);
        int ni = 0;
        for (int ee = 1; ee < 8; ++ee)
            if (cnt[ee] > cnt[ni]) ni = ee;   // first max == smallest on ties
        out[1] = (float)ni;
    }
}

extern "C" void kernel_launch(void* const* d_in, const int* in_sizes, int n_in,
                              void* d_out, int out_size, void* d_ws, size_t ws_size,
                              hipStream_t stream) {
    float* x           = (float*)d_in[0];   // normalized+bf16-packed in place
    const float* gamma = (const float*)d_in[1];
    const float* beta  = (const float*)d_in[2];
    const float* w1    = (const float*)d_in[3];
    const float* b1    = (const float*)d_in[4];
    const float* w2    = (const float*)d_in[5];
    const float* b2    = (const float*)d_in[6];
    const float* wr    = (const float*)d_in[7];
    const float* br    = (const float*)d_in[8];
    float* out = (float*)d_out;
    float* ws  = (float*)d_ws;

    float* hsum = ws;              // 4096 floats
    float* brd  = ws + 4096;       // 4096 floats (hsum..brd zeroed by prep)
    unsigned short* wt = (unsigned short*)(ws + 8192);   // 1M ushort (2MB)

    prep_kernel<<<dim3(M_DIM + 1024 + 32), dim3(256), 0, stream>>>(
        x, gamma, beta, w1, wt, ws);
    gemm_kernel<<<dim3(512), dim3(256), 0, stream>>>(
        (const unsigned short*)x, wt, b1, hsum);
    router1_kernel<<<dim3(8, 8), dim3(64, 4), 0, stream>>>(hsum, w2, b2, brd);
    router2_kernel<<<dim3(1), dim3(64, 8), 0, stream>>>(brd, wr, br, out);
}